// Round 10
// baseline (192.802 us; speedup 1.0000x reference)
//
#include <hip/hip_runtime.h>
#include <stdint.h>

#define B_  2
#define T_  2048
#define D_  1024
#define H_  16
#define HD_ 64
#define M_  (B_*T_)      // 4096
#define CHK 128          // time chunk
#define NC  (T_/CHK)     // 16
#define BH  (B_*H_)      // 32

#define XN   4194304     // x elems (4 M)
#define WN   1048576     // one W elems (1 M)

typedef unsigned short ushort_t;
typedef unsigned int   uint_t;

typedef __bf16 bf16x8 __attribute__((ext_vector_type(8)));
typedef float  f32x4  __attribute__((ext_vector_type(4)));

// ---------- bf16 helpers ----------
__device__ inline ushort_t f2bf(float f) {
    uint_t x = __float_as_uint(f);
    x += 0x7fffu + ((x >> 16) & 1u);   // RNE
    return (ushort_t)(x >> 16);
}

__device__ inline uint4 pack8(const float4& lo, const float4& hi) {
    uint4 pk;
    pk.x = (uint_t)f2bf(lo.x) | ((uint_t)f2bf(lo.y) << 16);
    pk.y = (uint_t)f2bf(lo.z) | ((uint_t)f2bf(lo.w) << 16);
    pk.z = (uint_t)f2bf(hi.x) | ((uint_t)f2bf(hi.y) << 16);
    pk.w = (uint_t)f2bf(hi.z) | ((uint_t)f2bf(hi.w) << 16);
    return pk;
}

// ---------------- fp32 -> bf16 pre-conversion (one contiguous dest) ----------------
__global__ __launch_bounds__(256) void to_bf16_all(
    const float* __restrict__ x,  const float* __restrict__ Wq,
    const float* __restrict__ Wk, const float* __restrict__ Wv,
    const float* __restrict__ Wo, ushort_t* __restrict__ dst)
{
    const int idx = blockIdx.x * 256 + threadIdx.x;
    const int e   = idx * 8;
    const float* src;
    if      (e < XN)          src = x  + e;
    else if (e < XN + WN)     src = Wq + (e - XN);
    else if (e < XN + 2*WN)   src = Wk + (e - XN - WN);
    else if (e < XN + 3*WN)   src = Wv + (e - XN - 2*WN);
    else                      src = Wo + (e - XN - 3*WN);
    float4 lo = ((const float4*)src)[0];
    float4 hi = ((const float4*)src)[1];
    *(uint4*)(dst + e) = pack8(lo, hi);
}

// ---------------- m97-style bf16 GEMM core pieces ----------------
__device__ inline void stage_rows(const ushort_t* __restrict__ g, ushort_t* ldsw,
                                  int lane, int issues) {
    const int rr  = lane >> 3;
    const int kg8 = ((lane & 7) ^ rr) << 3;
    const ushort_t* src = g + (size_t)rr * D_ + kg8;
    #pragma unroll
    for (int i = 0; i < issues; i++) {
        __builtin_amdgcn_global_load_lds(
            (const __attribute__((address_space(1))) void*)(src + (size_t)(i * 8) * D_),
            (__attribute__((address_space(3))) void*)(ldsw + i * 512),
            16, 0, 0);
    }
}
__device__ inline void stage32(const ushort_t* __restrict__ g, ushort_t* ldsw, int lane) {
    stage_rows(g, ldsw, lane, 4);
}

// Fused QKV projection from pre-converted bf16. Output [B,H,T,64] bf16.
// Epilogue: LDS repack (Cs, stride 132: conflict-free) -> dwordx4 stores
// (was 64 scalar 2-B stores/thread — mistake-class #2).
__global__ __launch_bounds__(256) void gemm_qkv(
    const ushort_t* __restrict__ xb, const ushort_t* __restrict__ Wqkvb,
    const float* __restrict__ bq, const float* __restrict__ bk,
    const float* __restrict__ bv, ushort_t* __restrict__ qkv_ws)
{
    const int z = blockIdx.z;
    const ushort_t* W  = Wqkvb + (size_t)z * WN;
    const float*    bi = (z == 0) ? bq : ((z == 1) ? bk : bv);
    ushort_t* out = qkv_ws + (size_t)z * (size_t)M_ * D_;

    __shared__ __align__(16) ushort_t As[128 * 64];
    __shared__ __align__(16) ushort_t Bs[128 * 64];
    __shared__ __align__(16) ushort_t Cs[64 * 132];   // epilogue repack, 16.9 KB

    const int tid  = threadIdx.x;
    const int m0   = blockIdx.y * 128;
    const int n0   = blockIdx.x * 128;
    const int wave = tid >> 6;
    const int lane = tid & 63;
    const int wm   = (wave >> 1) * 64;
    const int wn   = (wave & 1) * 64;
    const int fr   = lane & 15;
    const int quad = lane >> 4;

    const ushort_t* Ag = xb + (size_t)(m0 + wave * 32) * D_;
    const ushort_t* Bg = W  + (size_t)(n0 + wave * 32) * D_;
    ushort_t* Alds = &As[wave * 32 * 64];
    ushort_t* Blds = &Bs[wave * 32 * 64];

    f32x4 acc[4][4];
    #pragma unroll
    for (int i = 0; i < 4; i++)
        #pragma unroll
        for (int j = 0; j < 4; j++)
            acc[i][j] = (f32x4){0.f, 0.f, 0.f, 0.f};

    for (int k0 = 0; k0 < D_; k0 += 64) {
        __syncthreads();
        stage32(Ag + k0, Alds, lane);
        stage32(Bg + k0, Blds, lane);
        __syncthreads();

        #pragma unroll
        for (int ksg = 0; ksg <= 4; ksg += 4) {
            const int kgo = ((ksg + quad) ^ (fr & 7)) << 3;
            bf16x8 af[4], bf[4];
            #pragma unroll
            for (int i = 0; i < 4; i++) {
                uint4 u = *(const uint4*)&As[(wm + i * 16 + fr) * 64 + kgo];
                af[i] = __builtin_bit_cast(bf16x8, u);
            }
            #pragma unroll
            for (int j = 0; j < 4; j++) {
                uint4 u = *(const uint4*)&Bs[(wn + j * 16 + fr) * 64 + kgo];
                bf[j] = __builtin_bit_cast(bf16x8, u);
            }
            #pragma unroll
            for (int i = 0; i < 4; i++)
                #pragma unroll
                for (int j = 0; j < 4; j++)
                    acc[i][j] = __builtin_amdgcn_mfma_f32_16x16x32_bf16(
                        af[i], bf[j], acc[i][j], 0, 0, 0);
        }
    }

    // epilogue: two row-half passes through Cs; split heads with 16-B stores.
    const int rb = quad * 4;
    const int rl = tid >> 2;           // 0..63 local row
    const int ch = tid & 3;
    #pragma unroll
    for (int p = 0; p < 2; p++) {
        __syncthreads();
        if ((wave >> 1) == p) {
            #pragma unroll
            for (int j = 0; j < 4; j++) {
                const int n = n0 + wn + j * 16 + fr;
                const float bias = bi[n];
                #pragma unroll
                for (int i = 0; i < 4; i++)
                    #pragma unroll
                    for (int r = 0; r < 4; r++)
                        Cs[(i * 16 + rb + r) * 132 + wn + j * 16 + fr] =
                            f2bf(acc[i][j][r] + bias);
            }
        }
        __syncthreads();
        const int m = m0 + p * 64 + rl;
        const int b = m >> 11, t = m & (T_ - 1);
        #pragma unroll
        for (int g = 0; g < 4; g++) {
            const int c0 = ch * 8 + g * 32;
            const int n  = n0 + c0;
            const int h = n >> 6, hd = n & 63;
            uint4 u = *(const uint4*)&Cs[rl * 132 + c0];
            *(uint4*)&out[(((size_t)(b * H_ + h)) * T_ + t) * HD_ + hd] = u;
        }
    }
}

// Output projection: A = y_ws bf16 [M][D], B = Wob bf16, out fp32 + bias.
// Tile 64m x 128n -> 512 blocks = 2 blocks/CU.
__global__ __launch_bounds__(256) void gemm_out(
    const ushort_t* __restrict__ Yw, const ushort_t* __restrict__ Wob,
    const float* __restrict__ bo, float* __restrict__ out)
{
    __shared__ __align__(16) ushort_t As[64 * 64];
    __shared__ __align__(16) ushort_t Bs[128 * 64];

    const int tid  = threadIdx.x;
    const int m0   = blockIdx.y * 64;
    const int n0   = blockIdx.x * 128;
    const int wave = tid >> 6;
    const int lane = tid & 63;
    const int wm   = (wave >> 1) * 32;
    const int wn   = (wave & 1) * 64;
    const int fr   = lane & 15;
    const int quad = lane >> 4;

    const ushort_t* Ag = Yw  + (size_t)(m0 + wave * 16) * D_;
    const ushort_t* Bg = Wob + (size_t)(n0 + wave * 32) * D_;
    ushort_t* Alds = &As[wave * 16 * 64];
    ushort_t* Blds = &Bs[wave * 32 * 64];

    f32x4 acc[2][4];
    #pragma unroll
    for (int i = 0; i < 2; i++)
        #pragma unroll
        for (int j = 0; j < 4; j++)
            acc[i][j] = (f32x4){0.f, 0.f, 0.f, 0.f};

    for (int k0 = 0; k0 < D_; k0 += 64) {
        __syncthreads();
        stage_rows(Ag + k0, Alds, lane, 2);
        stage_rows(Bg + k0, Blds, lane, 4);
        __syncthreads();

        #pragma unroll
        for (int ksg = 0; ksg <= 4; ksg += 4) {
            const int kgo = ((ksg + quad) ^ (fr & 7)) << 3;
            bf16x8 af[2], bf[4];
            #pragma unroll
            for (int i = 0; i < 2; i++) {
                uint4 u = *(const uint4*)&As[(wm + i * 16 + fr) * 64 + kgo];
                af[i] = __builtin_bit_cast(bf16x8, u);
            }
            #pragma unroll
            for (int j = 0; j < 4; j++) {
                uint4 u = *(const uint4*)&Bs[(wn + j * 16 + fr) * 64 + kgo];
                bf[j] = __builtin_bit_cast(bf16x8, u);
            }
            #pragma unroll
            for (int i = 0; i < 2; i++)
                #pragma unroll
                for (int j = 0; j < 4; j++)
                    acc[i][j] = __builtin_amdgcn_mfma_f32_16x16x32_bf16(
                        af[i], bf[j], acc[i][j], 0, 0, 0);
        }
    }

    const int rb = quad * 4;
    #pragma unroll
    for (int j = 0; j < 4; j++) {
        const int n = n0 + wn + j * 16 + fr;
        const float bias = bo[n];
        #pragma unroll
        for (int i = 0; i < 2; i++) {
            #pragma unroll
            for (int r = 0; r < 4; r++) {
                const int m = m0 + wm + i * 16 + rb + r;
                out[(size_t)m * D_ + n] = acc[i][j][r] + bias;
            }
        }
    }
}

#define LDS_ 136   // row stride (ushorts): 272 B = 68 dwords = 4-bank rotation

// swizzled transpose scatter from registers: uint4 g of [128][64] tile ->
// dst[row][blk*8 + s&7], blk = (sb&8) | ((sb ^ (row>>3)) & 7).  (proven)
__device__ inline void scatter_T(const uint4* u, ushort_t* dst, int tid) {
    #pragma unroll
    for (int g = 0; g < 4; g++) {
        const int v  = tid + 256 * g;
        const int s  = v >> 3;
        const int p8 = (v & 7) * 8;
        ushort_t e[8];
        *(uint4*)e = u[g];
        const int sb = s >> 3, slo = s & 7;
        #pragma unroll
        for (int j = 0; j < 8; j++) {
            const int p   = p8 + j;
            const int blk = (sb & 8) | ((sb ^ (p >> 3)) & 7);
            dst[p * LDS_ + (blk << 3) + slo] = e[j];
        }
    }
}

__device__ inline void stage_T(const ushort_t* __restrict__ src, ushort_t* dst, int tid) {
    uint4 u[4];
    #pragma unroll
    for (int g = 0; g < 4; g++) u[g] = ((const uint4*)src)[tid + 256 * g];
    scatter_T(u, dst, tid);
}

// ---------------- fused chunk deltas + exclusive prefix (MFMA, reg-resident state) ---------
__global__ __launch_bounds__(256) void chunk_states(
    const ushort_t* __restrict__ k_ws, const ushort_t* __restrict__ v_ws,
    ushort_t* __restrict__ states_bf)
{
    const int bh = blockIdx.x;
    __shared__ __align__(16) ushort_t KtS[2][64 * LDS_];
    __shared__ __align__(16) ushort_t VtS[2][64 * LDS_];

    const int tid  = threadIdx.x;
    const int wave = tid >> 6, lane = tid & 63;
    const int fr = lane & 15, quad = lane >> 4, rb = quad * 4;
    const int p  = wave * 16 + fr;

    const uint4* kp = (const uint4*)(k_ws + (size_t)bh * T_ * HD_);
    const uint4* vp = (const uint4*)(v_ws + (size_t)bh * T_ * HD_);

    uint4 kv[4], vv[4];
    #pragma unroll
    for (int g = 0; g < 4; g++) {
        kv[g] = kp[tid + 256 * g];
        vv[g] = vp[tid + 256 * g];
    }

    f32x4 accs[4];
    #pragma unroll
    for (int jn = 0; jn < 4; jn++) accs[jn] = (f32x4){0.f, 0.f, 0.f, 0.f};

    for (int c = 0; c < NC; c++) {
        const int buf = c & 1;
        scatter_T(kv, KtS[buf], tid);
        scatter_T(vv, VtS[buf], tid);
        __syncthreads();

        if (c + 1 < NC) {
            const int off = (c + 1) * 1024;
            #pragma unroll
            for (int g = 0; g < 4; g++) {
                kv[g] = kp[off + tid + 256 * g];
                vv[g] = vp[off + tid + 256 * g];
            }
        }

        ushort_t* sp = states_bf + ((size_t)bh * NC + c) * 4096;
        #pragma unroll
        for (int jn = 0; jn < 4; jn++)
            #pragma unroll
            for (int r = 0; r < 4; r++)
                sp[(wave * 16 + rb + r) * 64 + jn * 16 + fr] = f2bf(accs[jn][r]);

        #pragma unroll
        for (int kt = 0; kt < 4; kt++) {
            const int sb   = kt * 4 + quad;
            const int blkA = (sb & 8) | ((sb ^ (p >> 3)) & 7);
            bf16x8 af = __builtin_bit_cast(bf16x8,
                *(const uint4*)&VtS[buf][p * LDS_ + (blkA << 3)]);
            #pragma unroll
            for (int jn = 0; jn < 4; jn++) {
                const int n    = jn * 16 + fr;
                const int blkB = (sb & 8) | ((sb ^ (n >> 3)) & 7);
                uint4 ub = *(const uint4*)&KtS[buf][n * LDS_ + (blkB << 3)];
                accs[jn] = __builtin_amdgcn_mfma_f32_16x16x32_bf16(
                    af, __builtin_bit_cast(bf16x8, ub), accs[jn], 0, 0, 0);
            }
        }
    }
}

// ---------------- per-chunk attention (MFMA, precomputed bf16 states) ----------------
// Epilogue: Y repacked through Smat (dead after PV) -> dwordx4 stores.
__global__ __launch_bounds__(256) void attn_chunk(
    const ushort_t* __restrict__ q_ws, const ushort_t* __restrict__ k_ws,
    const ushort_t* __restrict__ v_ws, const ushort_t* __restrict__ states_bf,
    ushort_t* __restrict__ y_ws)
{
    const int c = blockIdx.x, bh = blockIdx.y;
    __shared__ __align__(16) ushort_t VtS[64 * LDS_];    // V^T [p][s] swizzled
    __shared__ __align__(16) ushort_t Smat[128 * LDS_];  // scores, then Y repack

    const int tid  = threadIdx.x;
    const int wave = tid >> 6;
    const int lane = tid & 63;
    const int fr   = lane & 15;
    const int quad = lane >> 4;
    const int fk   = quad * 8;
    const int rb   = quad * 4;

    const size_t base = ((size_t)bh * T_ + (size_t)c * CHK) * HD_;
    const ushort_t* qg = q_ws + base;
    const ushort_t* kg = k_ws + base;
    const ushort_t* vg = v_ws + base;
    const ushort_t* st = states_bf + ((size_t)bh * NC + c) * 4096;

    stage_T(vg, VtS, tid);
    __syncthreads();

    const int mt[2] = { wave, 7 - wave };

    bf16x8 aq[2][2];
    #pragma unroll
    for (int i = 0; i < 2; i++)
        #pragma unroll
        for (int kk = 0; kk < 2; kk++) {
            uint4 u = *(const uint4*)(qg + (mt[i] * 16 + fr) * HD_ + kk * 32 + fk);
            aq[i][kk] = __builtin_bit_cast(bf16x8, u);
        }

    f32x4 acc[2][4];
    #pragma unroll
    for (int i = 0; i < 2; i++)
        #pragma unroll
        for (int jn = 0; jn < 4; jn++)
            acc[i][jn] = (f32x4){0.f, 0.f, 0.f, 0.f};

    // inter-chunk: acc += Q . S_prev^T (bf16 states direct)
    #pragma unroll
    for (int jn = 0; jn < 4; jn++) {
        #pragma unroll
        for (int kk = 0; kk < 2; kk++) {
            uint4 u = *(const uint4*)(st + (jn * 16 + fr) * 64 + kk * 32 + fk);
            bf16x8 bsp = __builtin_bit_cast(bf16x8, u);
            #pragma unroll
            for (int i = 0; i < 2; i++)
                acc[i][jn] = __builtin_amdgcn_mfma_f32_16x16x32_bf16(
                    aq[i][kk], bsp, acc[i][jn], 0, 0, 0);
        }
    }

    // per m-tile: scores -> mask -> Smat -> PV
    #pragma unroll
    for (int i = 0; i < 2; i++) {
        const int m  = mt[i];
        const int nk = (m + 2) >> 1;
        const int jt = 2 * nk;

        f32x4 sc[8];
        #pragma unroll
        for (int j = 0; j < 8; j++) sc[j] = (f32x4){0.f, 0.f, 0.f, 0.f};

        #pragma unroll
        for (int j = 0; j < 8; j++) {
            if (j <= m) {
                #pragma unroll
                for (int kk = 0; kk < 2; kk++) {
                    uint4 u = *(const uint4*)(kg + (j * 16 + fr) * HD_ + kk * 32 + fk);
                    sc[j] = __builtin_amdgcn_mfma_f32_16x16x32_bf16(
                        aq[i][kk], __builtin_bit_cast(bf16x8, u), sc[j], 0, 0, 0);
                }
            }
        }

        #pragma unroll
        for (int j = 0; j < 8; j++) {
            if (j < jt) {
                f32x4 v = sc[j];
                if (j == m) {
                    #pragma unroll
                    for (int r = 0; r < 4; r++)
                        if (fr > rb + r) v[r] = 0.f;
                }
                #pragma unroll
                for (int r = 0; r < 4; r++)
                    Smat[(m * 16 + rb + r) * LDS_ + j * 16 + fr] = f2bf(v[r]);
            }
        }

        #pragma unroll
        for (int kt = 0; kt < 4; kt++) {
            if (kt < nk) {
                uint4 ua = *(const uint4*)&Smat[(m * 16 + fr) * LDS_ + kt * 32 + fk];
                bf16x8 as_ = __builtin_bit_cast(bf16x8, ua);
                #pragma unroll
                for (int jn = 0; jn < 4; jn++) {
                    const int p   = jn * 16 + fr;
                    const int sb  = kt * 4 + quad;
                    const int blk = (sb & 8) | ((sb ^ (p >> 3)) & 7);
                    uint4 ub = *(const uint4*)&VtS[p * LDS_ + (blk << 3)];
                    acc[i][jn] = __builtin_amdgcn_mfma_f32_16x16x32_bf16(
                        as_, __builtin_bit_cast(bf16x8, ub), acc[i][jn], 0, 0, 0);
                }
            }
        }
    }

    // epilogue: repack Y rows into Smat (wave-private rows, in-order LDS), then
    // 16-B stores. (was 32 scalar 2-B stores/thread)
    #pragma unroll
    for (int i = 0; i < 2; i++)
        #pragma unroll
        for (int jn = 0; jn < 4; jn++)
            #pragma unroll
            for (int r = 0; r < 4; r++)
                Smat[(mt[i] * 16 + rb + r) * LDS_ + jn * 16 + fr] =
                    f2bf(acc[i][jn][r]);
    __syncthreads();

    const int b = bh >> 4, h = bh & 15;
    const int rl = tid >> 1, half = tid & 1;
    ushort_t* yr = y_ws + ((size_t)(b * T_ + c * CHK + rl)) * D_ + h * 64 + half * 32;
    #pragma unroll
    for (int g = 0; g < 4; g++) {
        uint4 u = *(const uint4*)&Smat[rl * LDS_ + half * 32 + g * 8];
        *(uint4*)&yr[g * 8] = u;
    }
}

// ---------------- launch ----------------
extern "C" void kernel_launch(void* const* d_in, const int* in_sizes, int n_in,
                              void* d_out, int out_size, void* d_ws, size_t ws_size,
                              hipStream_t stream)
{
    const float* x  = (const float*)d_in[0];
    const float* Wq = (const float*)d_in[1];
    const float* bq = (const float*)d_in[2];
    const float* Wk = (const float*)d_in[3];
    const float* bk = (const float*)d_in[4];
    const float* Wv = (const float*)d_in[5];
    const float* bv = (const float*)d_in[6];
    const float* Wo = (const float*)d_in[7];
    const float* bo = (const float*)d_in[8];
    float* out = (float*)d_out;

    // ws layout (ushort elems): [xb 4M][Wqb 1M][Wkb 1M][Wvb 1M][Wob 1M][q 4M][k 4M][v 4M][y 4M] = 48 MB
    ushort_t* cvt    = (ushort_t*)d_ws;
    ushort_t* xb     = cvt;
    ushort_t* Wqkvb  = cvt + (size_t)XN;
    ushort_t* Wob    = cvt + (size_t)XN + 3 * WN;
    ushort_t* q_ws   = cvt + (size_t)XN + 4 * WN;
    ushort_t* k_ws   = q_ws + (size_t)M_ * D_;
    ushort_t* v_ws   = k_ws + (size_t)M_ * D_;
    ushort_t* y_ws   = v_ws + (size_t)M_ * D_;
    ushort_t* states_bf = Wqkvb;   // alias into dead Wqb+Wkb region, 4 MB

    to_bf16_all<<<dim3((XN + 4 * WN) / 8 / 256), 256, 0, stream>>>(
        x, Wq, Wk, Wv, Wo, cvt);
    gemm_qkv<<<dim3(D_ / 128, M_ / 128, 3), 256, 0, stream>>>(
        xb, Wqkvb, bq, bk, bv, q_ws);
    chunk_states<<<dim3(BH), 256, 0, stream>>>(k_ws, v_ws, states_bf);
    attn_chunk<<<dim3(NC, BH), 256, 0, stream>>>(q_ws, k_ws, v_ws, states_bf, y_ws);
    gemm_out<<<dim3(D_ / 128, M_ / 64), 256, 0, stream>>>(y_ws, Wob, bo, out);
}

// Round 11
// 183.890 us; speedup vs baseline: 1.0485x; 1.0485x over previous
//
#include <hip/hip_runtime.h>
#include <stdint.h>

#define B_  2
#define T_  2048
#define D_  1024
#define H_  16
#define HD_ 64
#define M_  (B_*T_)      // 4096
#define CHK 128          // time chunk
#define NC  (T_/CHK)     // 16
#define BH  (B_*H_)      // 32

#define XN   4194304     // x elems (4 M)
#define WN   1048576     // one W elems (1 M)

typedef unsigned short ushort_t;
typedef unsigned int   uint_t;

typedef __bf16 bf16x8 __attribute__((ext_vector_type(8)));
typedef float  f32x4  __attribute__((ext_vector_type(4)));

// ---------- bf16 helpers ----------
__device__ inline ushort_t f2bf(float f) {
    uint_t x = __float_as_uint(f);
    x += 0x7fffu + ((x >> 16) & 1u);   // RNE
    return (ushort_t)(x >> 16);
}

__device__ inline uint4 pack8(const float4& lo, const float4& hi) {
    uint4 pk;
    pk.x = (uint_t)f2bf(lo.x) | ((uint_t)f2bf(lo.y) << 16);
    pk.y = (uint_t)f2bf(lo.z) | ((uint_t)f2bf(lo.w) << 16);
    pk.z = (uint_t)f2bf(hi.x) | ((uint_t)f2bf(hi.y) << 16);
    pk.w = (uint_t)f2bf(hi.z) | ((uint_t)f2bf(hi.w) << 16);
    return pk;
}

// ---------------- fp32 -> bf16 pre-conversion (one contiguous dest) ----------------
__global__ __launch_bounds__(256) void to_bf16_all(
    const float* __restrict__ x,  const float* __restrict__ Wq,
    const float* __restrict__ Wk, const float* __restrict__ Wv,
    const float* __restrict__ Wo, ushort_t* __restrict__ dst)
{
    const int idx = blockIdx.x * 256 + threadIdx.x;
    const int e   = idx * 8;
    const float* src;
    if      (e < XN)          src = x  + e;
    else if (e < XN + WN)     src = Wq + (e - XN);
    else if (e < XN + 2*WN)   src = Wk + (e - XN - WN);
    else if (e < XN + 3*WN)   src = Wv + (e - XN - 2*WN);
    else                      src = Wo + (e - XN - 3*WN);
    float4 lo = ((const float4*)src)[0];
    float4 hi = ((const float4*)src)[1];
    *(uint4*)(dst + e) = pack8(lo, hi);
}

// ---------------- m97-style bf16 GEMM core pieces ----------------
// LDS tiles are UNPADDED [rows][64] bf16 (required by global_load_lds lane-order
// placement); bank conflicts broken by XOR k-group swizzle applied on the
// GLOBAL pointer: LDS[r][kg] holds global k-group kg ^ (r&7).
__device__ inline void stage_rows(const ushort_t* __restrict__ g, ushort_t* ldsw,
                                  int lane, int issues) {
    const int rr  = lane >> 3;
    const int kg8 = ((lane & 7) ^ rr) << 3;
    const ushort_t* src = g + (size_t)rr * D_ + kg8;
    #pragma unroll
    for (int i = 0; i < issues; i++) {
        __builtin_amdgcn_global_load_lds(
            (const __attribute__((address_space(1))) void*)(src + (size_t)(i * 8) * D_),
            (__attribute__((address_space(3))) void*)(ldsw + i * 512),
            16, 0, 0);
    }
}
__device__ inline void stage32(const ushort_t* __restrict__ g, ushort_t* ldsw, int lane) {
    stage_rows(g, ldsw, lane, 4);
}

// Fused QKV projection from pre-converted bf16. Output [B,H,T,64] bf16.
// NOTE: scalar-store epilogue is deliberate — round-10's LDS-repack epilogue
// REGRESSED (45.2 -> 48.9 µs: +2 barriers, +17 KB LDS, bank conflicts). The
// scalar stores are hidden by 3-blocks/CU overlap.
__global__ __launch_bounds__(256) void gemm_qkv(
    const ushort_t* __restrict__ xb, const ushort_t* __restrict__ Wqkvb,
    const float* __restrict__ bq, const float* __restrict__ bk,
    const float* __restrict__ bv, ushort_t* __restrict__ qkv_ws)
{
    const int z = blockIdx.z;
    const ushort_t* W  = Wqkvb + (size_t)z * WN;
    const float*    bi = (z == 0) ? bq : ((z == 1) ? bk : bv);
    ushort_t* out = qkv_ws + (size_t)z * (size_t)M_ * D_;

    __shared__ __align__(16) ushort_t As[128 * 64];
    __shared__ __align__(16) ushort_t Bs[128 * 64];

    const int tid  = threadIdx.x;
    const int m0   = blockIdx.y * 128;
    const int n0   = blockIdx.x * 128;
    const int wave = tid >> 6;
    const int lane = tid & 63;
    const int wm   = (wave >> 1) * 64;
    const int wn   = (wave & 1) * 64;
    const int fr   = lane & 15;
    const int quad = lane >> 4;

    const ushort_t* Ag = xb + (size_t)(m0 + wave * 32) * D_;
    const ushort_t* Bg = W  + (size_t)(n0 + wave * 32) * D_;
    ushort_t* Alds = &As[wave * 32 * 64];
    ushort_t* Blds = &Bs[wave * 32 * 64];

    f32x4 acc[4][4];
    #pragma unroll
    for (int i = 0; i < 4; i++)
        #pragma unroll
        for (int j = 0; j < 4; j++)
            acc[i][j] = (f32x4){0.f, 0.f, 0.f, 0.f};

    for (int k0 = 0; k0 < D_; k0 += 64) {
        __syncthreads();
        stage32(Ag + k0, Alds, lane);
        stage32(Bg + k0, Blds, lane);
        __syncthreads();

        #pragma unroll
        for (int ksg = 0; ksg <= 4; ksg += 4) {
            const int kgo = ((ksg + quad) ^ (fr & 7)) << 3;
            bf16x8 af[4], bf[4];
            #pragma unroll
            for (int i = 0; i < 4; i++) {
                uint4 u = *(const uint4*)&As[(wm + i * 16 + fr) * 64 + kgo];
                af[i] = __builtin_bit_cast(bf16x8, u);
            }
            #pragma unroll
            for (int j = 0; j < 4; j++) {
                uint4 u = *(const uint4*)&Bs[(wn + j * 16 + fr) * 64 + kgo];
                bf[j] = __builtin_bit_cast(bf16x8, u);
            }
            #pragma unroll
            for (int i = 0; i < 4; i++)
                #pragma unroll
                for (int j = 0; j < 4; j++)
                    acc[i][j] = __builtin_amdgcn_mfma_f32_16x16x32_bf16(
                        af[i], bf[j], acc[i][j], 0, 0, 0);
        }
    }

    // epilogue: D[row=quad*4+r, col=fr] per 16x16 tile; split heads.
    const int rb = quad * 4;
    #pragma unroll
    for (int j = 0; j < 4; j++) {
        const int n = n0 + wn + j * 16 + fr;
        const float bias = bi[n];
        const int h  = n >> 6;
        const int hd = n & 63;
        #pragma unroll
        for (int i = 0; i < 4; i++) {
            #pragma unroll
            for (int r = 0; r < 4; r++) {
                const int m = m0 + wm + i * 16 + rb + r;
                const int b = m >> 11, t = m & (T_ - 1);
                out[(((size_t)(b * H_ + h)) * T_ + t) * HD_ + hd] =
                    f2bf(acc[i][j][r] + bias);
            }
        }
    }
}

// Output projection: A = y_ws bf16 [M][D], B = Wob bf16, out fp32 + bias.
// Tile 64m x 128n -> 512 blocks = 2 blocks/CU.
__global__ __launch_bounds__(256) void gemm_out(
    const ushort_t* __restrict__ Yw, const ushort_t* __restrict__ Wob,
    const float* __restrict__ bo, float* __restrict__ out)
{
    __shared__ __align__(16) ushort_t As[64 * 64];
    __shared__ __align__(16) ushort_t Bs[128 * 64];

    const int tid  = threadIdx.x;
    const int m0   = blockIdx.y * 64;
    const int n0   = blockIdx.x * 128;
    const int wave = tid >> 6;
    const int lane = tid & 63;
    const int wm   = (wave >> 1) * 32;
    const int wn   = (wave & 1) * 64;
    const int fr   = lane & 15;
    const int quad = lane >> 4;

    const ushort_t* Ag = Yw  + (size_t)(m0 + wave * 16) * D_;
    const ushort_t* Bg = Wob + (size_t)(n0 + wave * 32) * D_;
    ushort_t* Alds = &As[wave * 16 * 64];
    ushort_t* Blds = &Bs[wave * 32 * 64];

    f32x4 acc[2][4];
    #pragma unroll
    for (int i = 0; i < 2; i++)
        #pragma unroll
        for (int j = 0; j < 4; j++)
            acc[i][j] = (f32x4){0.f, 0.f, 0.f, 0.f};

    for (int k0 = 0; k0 < D_; k0 += 64) {
        __syncthreads();
        stage_rows(Ag + k0, Alds, lane, 2);
        stage_rows(Bg + k0, Blds, lane, 4);
        __syncthreads();

        #pragma unroll
        for (int ksg = 0; ksg <= 4; ksg += 4) {
            const int kgo = ((ksg + quad) ^ (fr & 7)) << 3;
            bf16x8 af[2], bf[4];
            #pragma unroll
            for (int i = 0; i < 2; i++) {
                uint4 u = *(const uint4*)&As[(wm + i * 16 + fr) * 64 + kgo];
                af[i] = __builtin_bit_cast(bf16x8, u);
            }
            #pragma unroll
            for (int j = 0; j < 4; j++) {
                uint4 u = *(const uint4*)&Bs[(wn + j * 16 + fr) * 64 + kgo];
                bf[j] = __builtin_bit_cast(bf16x8, u);
            }
            #pragma unroll
            for (int i = 0; i < 2; i++)
                #pragma unroll
                for (int j = 0; j < 4; j++)
                    acc[i][j] = __builtin_amdgcn_mfma_f32_16x16x32_bf16(
                        af[i], bf[j], acc[i][j], 0, 0, 0);
        }
    }

    const int rb = quad * 4;
    #pragma unroll
    for (int j = 0; j < 4; j++) {
        const int n = n0 + wn + j * 16 + fr;
        const float bias = bo[n];
        #pragma unroll
        for (int i = 0; i < 2; i++) {
            #pragma unroll
            for (int r = 0; r < 4; r++) {
                const int m = m0 + wm + i * 16 + rb + r;
                out[(size_t)m * D_ + n] = acc[i][j][r] + bias;
            }
        }
    }
}

#define LDS_ 136   // row stride (ushorts): 272 B = 68 dwords = 4-bank rotation

// swizzled transpose scatter from registers: uint4 g of [128][64] tile ->
// dst[row][blk*8 + s&7], blk = (sb&8) | ((sb ^ (row>>3)) & 7).  (proven)
__device__ inline void scatter_T(const uint4* u, ushort_t* dst, int tid) {
    #pragma unroll
    for (int g = 0; g < 4; g++) {
        const int v  = tid + 256 * g;
        const int s  = v >> 3;
        const int p8 = (v & 7) * 8;
        ushort_t e[8];
        *(uint4*)e = u[g];
        const int sb = s >> 3, slo = s & 7;
        #pragma unroll
        for (int j = 0; j < 8; j++) {
            const int p   = p8 + j;
            const int blk = (sb & 8) | ((sb ^ (p >> 3)) & 7);
            dst[p * LDS_ + (blk << 3) + slo] = e[j];
        }
    }
}

__device__ inline void stage_T(const ushort_t* __restrict__ src, ushort_t* dst, int tid) {
    uint4 u[4];
    #pragma unroll
    for (int g = 0; g < 4; g++) u[g] = ((const uint4*)src)[tid + 256 * g];
    scatter_T(u, dst, tid);
}

// ---------------- fused chunk deltas + exclusive prefix, n-split 4x ----------------
// Grid (4, BH) = 128 blocks (was 32 = 1 block/8 CUs, zero latency hiding).
// Block (jn, bh) owns n-tile jn: stages full V^T (A) + 16-row K^T slice (B),
// 4 MFMAs/chunk/wave, state slice in 1 f32x4/thread. Accumulation order per
// (p,n) element identical to the unsplit version -> bit-identical states.
__global__ __launch_bounds__(256) void chunk_states(
    const ushort_t* __restrict__ k_ws, const ushort_t* __restrict__ v_ws,
    ushort_t* __restrict__ states_bf)
{
    const int jn = blockIdx.x;          // n-tile 0..3
    const int bh = blockIdx.y;
    __shared__ __align__(16) ushort_t VtS[2][64 * LDS_];   // 34 KB
    __shared__ __align__(16) ushort_t KtS[2][16 * LDS_];   // 8.5 KB

    const int tid  = threadIdx.x;
    const int wave = tid >> 6, lane = tid & 63;
    const int fr = lane & 15, quad = lane >> 4, rb = quad * 4;
    const int p  = wave * 16 + fr;

    const ushort_t* kb = k_ws + (size_t)bh * T_ * HD_ + jn * 16;
    const uint4*    vp = (const uint4*)(v_ws + (size_t)bh * T_ * HD_);

    // K-slice pattern: thread -> (s = tid>>1, n-group = (tid&1)*8)
    const int ks = tid >> 1;
    const int ng = (tid & 1) * 8;

    uint4 kv = *(const uint4*)(kb + ks * HD_ + ng);
    uint4 vv[4];
    #pragma unroll
    for (int g = 0; g < 4; g++) vv[g] = vp[tid + 256 * g];

    f32x4 accs = (f32x4){0.f, 0.f, 0.f, 0.f};

    for (int c = 0; c < NC; c++) {
        const int buf = c & 1;
        scatter_T(vv, VtS[buf], tid);
        {   // scatter K slice: 8 ushorts, local row nl = ng + j
            ushort_t e[8];
            *(uint4*)e = kv;
            const int sb = ks >> 3, slo = ks & 7;
            #pragma unroll
            for (int j = 0; j < 8; j++) {
                const int nl  = ng + j;
                const int blk = (sb & 8) | ((sb ^ (nl >> 3)) & 7);
                KtS[buf][nl * LDS_ + (blk << 3) + slo] = e[j];
            }
        }
        __syncthreads();

        if (c + 1 < NC) {   // register prefetch next chunk (overlaps MFMA)
            kv = *(const uint4*)(kb + (size_t)(c + 1) * CHK * HD_ + ks * HD_ + ng);
            const int off = (c + 1) * 1024;
            #pragma unroll
            for (int g = 0; g < 4; g++) vv[g] = vp[off + tid + 256 * g];
        }

        // exclusive prefix: store state slice BEFORE adding this chunk's delta
        ushort_t* sp = states_bf + ((size_t)bh * NC + c) * 4096;
        #pragma unroll
        for (int r = 0; r < 4; r++)
            sp[(wave * 16 + rb + r) * 64 + jn * 16 + fr] = f2bf(accs[r]);

        #pragma unroll
        for (int kt = 0; kt < 4; kt++) {
            const int sb   = kt * 4 + quad;
            const int blkA = (sb & 8) | ((sb ^ (p >> 3)) & 7);
            bf16x8 af = __builtin_bit_cast(bf16x8,
                *(const uint4*)&VtS[buf][p * LDS_ + (blkA << 3)]);
            const int blkB = (sb & 8) | ((sb ^ (fr >> 3)) & 7);
            uint4 ub = *(const uint4*)&KtS[buf][fr * LDS_ + (blkB << 3)];
            accs = __builtin_amdgcn_mfma_f32_16x16x32_bf16(
                af, __builtin_bit_cast(bf16x8, ub), accs, 0, 0, 0);
        }
        // dbuf LDS: next iteration scatters the other buffer, barrier each iter
    }
}

// ---------------- per-chunk attention (MFMA, precomputed bf16 states) ----------------
// Scalar-store epilogue deliberate (round-10 repack regressed).
__global__ __launch_bounds__(256) void attn_chunk(
    const ushort_t* __restrict__ q_ws, const ushort_t* __restrict__ k_ws,
    const ushort_t* __restrict__ v_ws, const ushort_t* __restrict__ states_bf,
    ushort_t* __restrict__ y_ws)
{
    const int c = blockIdx.x, bh = blockIdx.y;
    __shared__ __align__(16) ushort_t VtS[64 * LDS_];    // V^T [p][s] swizzled
    __shared__ __align__(16) ushort_t Smat[128 * LDS_];  // masked scores [t][s]

    const int tid  = threadIdx.x;
    const int wave = tid >> 6;
    const int lane = tid & 63;
    const int fr   = lane & 15;
    const int quad = lane >> 4;
    const int fk   = quad * 8;
    const int rb   = quad * 4;

    const size_t base = ((size_t)bh * T_ + (size_t)c * CHK) * HD_;
    const ushort_t* qg = q_ws + base;
    const ushort_t* kg = k_ws + base;
    const ushort_t* vg = v_ws + base;
    const ushort_t* st = states_bf + ((size_t)bh * NC + c) * 4096;

    stage_T(vg, VtS, tid);
    __syncthreads();

    const int mt[2] = { wave, 7 - wave };

    bf16x8 aq[2][2];
    #pragma unroll
    for (int i = 0; i < 2; i++)
        #pragma unroll
        for (int kk = 0; kk < 2; kk++) {
            uint4 u = *(const uint4*)(qg + (mt[i] * 16 + fr) * HD_ + kk * 32 + fk);
            aq[i][kk] = __builtin_bit_cast(bf16x8, u);
        }

    f32x4 acc[2][4];
    #pragma unroll
    for (int i = 0; i < 2; i++)
        #pragma unroll
        for (int jn = 0; jn < 4; jn++)
            acc[i][jn] = (f32x4){0.f, 0.f, 0.f, 0.f};

    // inter-chunk: acc += Q . S_prev^T (bf16 states direct)
    #pragma unroll
    for (int jn = 0; jn < 4; jn++) {
        #pragma unroll
        for (int kk = 0; kk < 2; kk++) {
            uint4 u = *(const uint4*)(st + (jn * 16 + fr) * 64 + kk * 32 + fk);
            bf16x8 bsp = __builtin_bit_cast(bf16x8, u);
            #pragma unroll
            for (int i = 0; i < 2; i++)
                acc[i][jn] = __builtin_amdgcn_mfma_f32_16x16x32_bf16(
                    aq[i][kk], bsp, acc[i][jn], 0, 0, 0);
        }
    }

    // per m-tile: scores -> mask -> Smat -> PV
    #pragma unroll
    for (int i = 0; i < 2; i++) {
        const int m  = mt[i];
        const int nk = (m + 2) >> 1;
        const int jt = 2 * nk;

        f32x4 sc[8];
        #pragma unroll
        for (int j = 0; j < 8; j++) sc[j] = (f32x4){0.f, 0.f, 0.f, 0.f};

        #pragma unroll
        for (int j = 0; j < 8; j++) {
            if (j <= m) {
                #pragma unroll
                for (int kk = 0; kk < 2; kk++) {
                    uint4 u = *(const uint4*)(kg + (j * 16 + fr) * HD_ + kk * 32 + fk);
                    sc[j] = __builtin_amdgcn_mfma_f32_16x16x32_bf16(
                        aq[i][kk], __builtin_bit_cast(bf16x8, u), sc[j], 0, 0, 0);
                }
            }
        }

        #pragma unroll
        for (int j = 0; j < 8; j++) {
            if (j < jt) {
                f32x4 v = sc[j];
                if (j == m) {
                    #pragma unroll
                    for (int r = 0; r < 4; r++)
                        if (fr > rb + r) v[r] = 0.f;
                }
                #pragma unroll
                for (int r = 0; r < 4; r++)
                    Smat[(m * 16 + rb + r) * LDS_ + j * 16 + fr] = f2bf(v[r]);
            }
        }

        #pragma unroll
        for (int kt = 0; kt < 4; kt++) {
            if (kt < nk) {
                uint4 ua = *(const uint4*)&Smat[(m * 16 + fr) * LDS_ + kt * 32 + fk];
                bf16x8 as_ = __builtin_bit_cast(bf16x8, ua);
                #pragma unroll
                for (int jn = 0; jn < 4; jn++) {
                    const int p   = jn * 16 + fr;
                    const int sb  = kt * 4 + quad;
                    const int blk = (sb & 8) | ((sb ^ (p >> 3)) & 7);
                    uint4 ub = *(const uint4*)&VtS[p * LDS_ + (blk << 3)];
                    acc[i][jn] = __builtin_amdgcn_mfma_f32_16x16x32_bf16(
                        as_, __builtin_bit_cast(bf16x8, ub), acc[i][jn], 0, 0, 0);
                }
            }
        }
    }

    const int b = bh >> 4, h = bh & 15;
    ushort_t* yg = y_ws + ((size_t)(b * T_ + c * CHK)) * D_ + h * 64;
    #pragma unroll
    for (int i = 0; i < 2; i++) {
        #pragma unroll
        for (int jn = 0; jn < 4; jn++) {
            #pragma unroll
            for (int r = 0; r < 4; r++) {
                const int t = mt[i] * 16 + rb + r;
                const int p = jn * 16 + fr;
                yg[(size_t)t * D_ + p] = f2bf(acc[i][jn][r]);
            }
        }
    }
}

// ---------------- launch ----------------
extern "C" void kernel_launch(void* const* d_in, const int* in_sizes, int n_in,
                              void* d_out, int out_size, void* d_ws, size_t ws_size,
                              hipStream_t stream)
{
    const float* x  = (const float*)d_in[0];
    const float* Wq = (const float*)d_in[1];
    const float* bq = (const float*)d_in[2];
    const float* Wk = (const float*)d_in[3];
    const float* bk = (const float*)d_in[4];
    const float* Wv = (const float*)d_in[5];
    const float* bv = (const float*)d_in[6];
    const float* Wo = (const float*)d_in[7];
    const float* bo = (const float*)d_in[8];
    float* out = (float*)d_out;

    // ws layout (ushort elems): [xb 4M][Wqb 1M][Wkb 1M][Wvb 1M][Wob 1M][q 4M][k 4M][v 4M][y 4M] = 48 MB
    ushort_t* cvt    = (ushort_t*)d_ws;
    ushort_t* xb     = cvt;
    ushort_t* Wqkvb  = cvt + (size_t)XN;
    ushort_t* Wob    = cvt + (size_t)XN + 3 * WN;
    ushort_t* q_ws   = cvt + (size_t)XN + 4 * WN;
    ushort_t* k_ws   = q_ws + (size_t)M_ * D_;
    ushort_t* v_ws   = k_ws + (size_t)M_ * D_;
    ushort_t* y_ws   = v_ws + (size_t)M_ * D_;
    ushort_t* states_bf = Wqkvb;   // alias into dead Wqb+Wkb region, 4 MB

    to_bf16_all<<<dim3((XN + 4 * WN) / 8 / 256), 256, 0, stream>>>(
        x, Wq, Wk, Wv, Wo, cvt);
    gemm_qkv<<<dim3(D_ / 128, M_ / 128, 3), 256, 0, stream>>>(
        xb, Wqkvb, bq, bk, bv, q_ws);
    chunk_states<<<dim3(4, BH), 256, 0, stream>>>(k_ws, v_ws, states_bf);
    attn_chunk<<<dim3(NC, BH), 256, 0, stream>>>(q_ws, k_ws, v_ws, states_bf, y_ws);
    gemm_out<<<dim3(D_ / 128, M_ / 64), 256, 0, stream>>>(y_ws, Wob, bo, out);
}

// Round 12
// 181.079 us; speedup vs baseline: 1.0647x; 1.0155x over previous
//
#include <hip/hip_runtime.h>
#include <stdint.h>

#define B_  2
#define T_  2048
#define D_  1024
#define H_  16
#define HD_ 64
#define M_  (B_*T_)      // 4096
#define CHK 128          // time chunk
#define NC  (T_/CHK)     // 16
#define BH  (B_*H_)      // 32

#define XN   4194304     // x elems (4 M)
#define WN   1048576     // one W elems (1 M)

typedef unsigned short ushort_t;
typedef unsigned int   uint_t;

typedef __bf16 bf16x8 __attribute__((ext_vector_type(8)));
typedef float  f32x4  __attribute__((ext_vector_type(4)));

// ---------- bf16 helpers ----------
__device__ inline ushort_t f2bf(float f) {
    uint_t x = __float_as_uint(f);
    x += 0x7fffu + ((x >> 16) & 1u);   // RNE
    return (ushort_t)(x >> 16);
}

__device__ inline uint4 pack8(const float4& lo, const float4& hi) {
    uint4 pk;
    pk.x = (uint_t)f2bf(lo.x) | ((uint_t)f2bf(lo.y) << 16);
    pk.y = (uint_t)f2bf(lo.z) | ((uint_t)f2bf(lo.w) << 16);
    pk.z = (uint_t)f2bf(hi.x) | ((uint_t)f2bf(hi.y) << 16);
    pk.w = (uint_t)f2bf(hi.z) | ((uint_t)f2bf(hi.w) << 16);
    return pk;
}

// ---------------- fp32 -> bf16 pre-conversion (one contiguous dest) ----------------
__global__ __launch_bounds__(256) void to_bf16_all(
    const float* __restrict__ x,  const float* __restrict__ Wq,
    const float* __restrict__ Wk, const float* __restrict__ Wv,
    const float* __restrict__ Wo, ushort_t* __restrict__ dst)
{
    const int idx = blockIdx.x * 256 + threadIdx.x;
    const int e   = idx * 8;
    const float* src;
    if      (e < XN)          src = x  + e;
    else if (e < XN + WN)     src = Wq + (e - XN);
    else if (e < XN + 2*WN)   src = Wk + (e - XN - WN);
    else if (e < XN + 3*WN)   src = Wv + (e - XN - 2*WN);
    else                      src = Wo + (e - XN - 3*WN);
    float4 lo = ((const float4*)src)[0];
    float4 hi = ((const float4*)src)[1];
    *(uint4*)(dst + e) = pack8(lo, hi);
}

// ---------------- m97-style bf16 GEMM core pieces ----------------
__device__ inline void stage_rows(const ushort_t* __restrict__ g, ushort_t* ldsw,
                                  int lane, int issues) {
    const int rr  = lane >> 3;
    const int kg8 = ((lane & 7) ^ rr) << 3;
    const ushort_t* src = g + (size_t)rr * D_ + kg8;
    #pragma unroll
    for (int i = 0; i < issues; i++) {
        __builtin_amdgcn_global_load_lds(
            (const __attribute__((address_space(1))) void*)(src + (size_t)(i * 8) * D_),
            (__attribute__((address_space(3))) void*)(ldsw + i * 512),
            16, 0, 0);
    }
}
__device__ inline void stage32(const ushort_t* __restrict__ g, ushort_t* ldsw, int lane) {
    stage_rows(g, ldsw, lane, 4);
}

// Fused QKV projection from pre-converted bf16. Output [B,H,T,64] bf16.
// 1-D grid of 768 with XCD-rectangle decode: XCD r = flat%8 owns an
// 8 m-tile x 4 n-tile x 3 z rectangle (96 blocks = one XCD's full residency).
// A-tiles fetched into 2 XCDs instead of 8, W into 4 -> FETCH ~68.7 -> ~40 MB.
__global__ __launch_bounds__(256) void gemm_qkv(
    const ushort_t* __restrict__ xb, const ushort_t* __restrict__ Wqkvb,
    const float* __restrict__ bq, const float* __restrict__ bk,
    const float* __restrict__ bv, ushort_t* __restrict__ qkv_ws)
{
    const int flat = blockIdx.x;          // 0..767
    const int r    = flat & 7;            // XCD (assumed flat%8 placement)
    const int j    = flat >> 3;           // 0..95
    const int mt   = ((r >> 1) << 3) | (j & 7);          // m-tile 0..31
    const int nt   = ((r & 1) << 2) | ((j >> 3) & 3);    // n-tile 0..7
    const int z    = j >> 5;                             // 0..2

    const ushort_t* W  = Wqkvb + (size_t)z * WN;
    const float*    bi = (z == 0) ? bq : ((z == 1) ? bk : bv);
    ushort_t* out = qkv_ws + (size_t)z * (size_t)M_ * D_;

    __shared__ __align__(16) ushort_t As[128 * 64];
    __shared__ __align__(16) ushort_t Bs[128 * 64];

    const int tid  = threadIdx.x;
    const int m0   = mt * 128;
    const int n0   = nt * 128;
    const int wave = tid >> 6;
    const int lane = tid & 63;
    const int wm   = (wave >> 1) * 64;
    const int wn   = (wave & 1) * 64;
    const int fr   = lane & 15;
    const int quad = lane >> 4;

    const ushort_t* Ag = xb + (size_t)(m0 + wave * 32) * D_;
    const ushort_t* Bg = W  + (size_t)(n0 + wave * 32) * D_;
    ushort_t* Alds = &As[wave * 32 * 64];
    ushort_t* Blds = &Bs[wave * 32 * 64];

    f32x4 acc[4][4];
    #pragma unroll
    for (int i = 0; i < 4; i++)
        #pragma unroll
        for (int j2 = 0; j2 < 4; j2++)
            acc[i][j2] = (f32x4){0.f, 0.f, 0.f, 0.f};

    for (int k0 = 0; k0 < D_; k0 += 64) {
        __syncthreads();
        stage32(Ag + k0, Alds, lane);
        stage32(Bg + k0, Blds, lane);
        __syncthreads();

        #pragma unroll
        for (int ksg = 0; ksg <= 4; ksg += 4) {
            const int kgo = ((ksg + quad) ^ (fr & 7)) << 3;
            bf16x8 af[4], bf[4];
            #pragma unroll
            for (int i = 0; i < 4; i++) {
                uint4 u = *(const uint4*)&As[(wm + i * 16 + fr) * 64 + kgo];
                af[i] = __builtin_bit_cast(bf16x8, u);
            }
            #pragma unroll
            for (int j2 = 0; j2 < 4; j2++) {
                uint4 u = *(const uint4*)&Bs[(wn + j2 * 16 + fr) * 64 + kgo];
                bf[j2] = __builtin_bit_cast(bf16x8, u);
            }
            #pragma unroll
            for (int i = 0; i < 4; i++)
                #pragma unroll
                for (int j2 = 0; j2 < 4; j2++)
                    acc[i][j2] = __builtin_amdgcn_mfma_f32_16x16x32_bf16(
                        af[i], bf[j2], acc[i][j2], 0, 0, 0);
        }
    }

    // epilogue: D[row=quad*4+r, col=fr] per 16x16 tile; split heads.
    // (scalar stores deliberate — round-10 LDS repack regressed)
    const int rb = quad * 4;
    #pragma unroll
    for (int j2 = 0; j2 < 4; j2++) {
        const int n = n0 + wn + j2 * 16 + fr;
        const float bias = bi[n];
        const int h  = n >> 6;
        const int hd = n & 63;
        #pragma unroll
        for (int i = 0; i < 4; i++) {
            #pragma unroll
            for (int rr = 0; rr < 4; rr++) {
                const int m = m0 + wm + i * 16 + rb + rr;
                const int b = m >> 11, t = m & (T_ - 1);
                out[(((size_t)(b * H_ + h)) * T_ + t) * HD_ + hd] =
                    f2bf(acc[i][j2][rr] + bias);
            }
        }
    }
}

// Output projection: A = y_ws bf16 [M][D], B = Wob bf16, out fp32 + bias.
// Tile 64m x 128n, 1-D grid 512, XCD rectangle 16m x 4n per XCD.
__global__ __launch_bounds__(256) void gemm_out(
    const ushort_t* __restrict__ Yw, const ushort_t* __restrict__ Wob,
    const float* __restrict__ bo, float* __restrict__ out)
{
    const int flat = blockIdx.x;          // 0..511
    const int r    = flat & 7;
    const int j    = flat >> 3;           // 0..63
    const int mt   = ((r >> 1) << 4) | (j & 15);   // 0..63
    const int nt   = ((r & 1) << 2) | (j >> 4);    // 0..7

    __shared__ __align__(16) ushort_t As[64 * 64];
    __shared__ __align__(16) ushort_t Bs[128 * 64];

    const int tid  = threadIdx.x;
    const int m0   = mt * 64;
    const int n0   = nt * 128;
    const int wave = tid >> 6;
    const int lane = tid & 63;
    const int wm   = (wave >> 1) * 32;
    const int wn   = (wave & 1) * 64;
    const int fr   = lane & 15;
    const int quad = lane >> 4;

    const ushort_t* Ag = Yw  + (size_t)(m0 + wave * 16) * D_;
    const ushort_t* Bg = Wob + (size_t)(n0 + wave * 32) * D_;
    ushort_t* Alds = &As[wave * 16 * 64];
    ushort_t* Blds = &Bs[wave * 32 * 64];

    f32x4 acc[2][4];
    #pragma unroll
    for (int i = 0; i < 2; i++)
        #pragma unroll
        for (int j2 = 0; j2 < 4; j2++)
            acc[i][j2] = (f32x4){0.f, 0.f, 0.f, 0.f};

    for (int k0 = 0; k0 < D_; k0 += 64) {
        __syncthreads();
        stage_rows(Ag + k0, Alds, lane, 2);
        stage_rows(Bg + k0, Blds, lane, 4);
        __syncthreads();

        #pragma unroll
        for (int ksg = 0; ksg <= 4; ksg += 4) {
            const int kgo = ((ksg + quad) ^ (fr & 7)) << 3;
            bf16x8 af[2], bf[4];
            #pragma unroll
            for (int i = 0; i < 2; i++) {
                uint4 u = *(const uint4*)&As[(wm + i * 16 + fr) * 64 + kgo];
                af[i] = __builtin_bit_cast(bf16x8, u);
            }
            #pragma unroll
            for (int j2 = 0; j2 < 4; j2++) {
                uint4 u = *(const uint4*)&Bs[(wn + j2 * 16 + fr) * 64 + kgo];
                bf[j2] = __builtin_bit_cast(bf16x8, u);
            }
            #pragma unroll
            for (int i = 0; i < 2; i++)
                #pragma unroll
                for (int j2 = 0; j2 < 4; j2++)
                    acc[i][j2] = __builtin_amdgcn_mfma_f32_16x16x32_bf16(
                        af[i], bf[j2], acc[i][j2], 0, 0, 0);
        }
    }

    const int rb = quad * 4;
    #pragma unroll
    for (int j2 = 0; j2 < 4; j2++) {
        const int n = n0 + wn + j2 * 16 + fr;
        const float bias = bo[n];
        #pragma unroll
        for (int i = 0; i < 2; i++) {
            #pragma unroll
            for (int rr = 0; rr < 4; rr++) {
                const int m = m0 + wm + i * 16 + rb + rr;
                out[(size_t)m * D_ + n] = acc[i][j2][rr] + bias;
            }
        }
    }
}

#define LDS_ 136   // row stride (ushorts): 272 B = 68 dwords = 4-bank rotation

// swizzled transpose scatter from registers: uint4 g of [128][64] tile ->
// dst[row][blk*8 + s&7], blk = (sb&8) | ((sb ^ (row>>3)) & 7).  (proven)
__device__ inline void scatter_T(const uint4* u, ushort_t* dst, int tid) {
    #pragma unroll
    for (int g = 0; g < 4; g++) {
        const int v  = tid + 256 * g;
        const int s  = v >> 3;
        const int p8 = (v & 7) * 8;
        ushort_t e[8];
        *(uint4*)e = u[g];
        const int sb = s >> 3, slo = s & 7;
        #pragma unroll
        for (int j = 0; j < 8; j++) {
            const int p   = p8 + j;
            const int blk = (sb & 8) | ((sb ^ (p >> 3)) & 7);
            dst[p * LDS_ + (blk << 3) + slo] = e[j];
        }
    }
}

__device__ inline void stage_T(const ushort_t* __restrict__ src, ushort_t* dst, int tid) {
    uint4 u[4];
    #pragma unroll
    for (int g = 0; g < 4; g++) u[g] = ((const uint4*)src)[tid + 256 * g];
    scatter_T(u, dst, tid);
}

// ---------------- fused chunk deltas + exclusive prefix, n-split 4x ----------------
__global__ __launch_bounds__(256) void chunk_states(
    const ushort_t* __restrict__ k_ws, const ushort_t* __restrict__ v_ws,
    ushort_t* __restrict__ states_bf)
{
    const int jn = blockIdx.x;          // n-tile 0..3
    const int bh = blockIdx.y;
    __shared__ __align__(16) ushort_t VtS[2][64 * LDS_];   // 34 KB
    __shared__ __align__(16) ushort_t KtS[2][16 * LDS_];   // 8.5 KB

    const int tid  = threadIdx.x;
    const int wave = tid >> 6, lane = tid & 63;
    const int fr = lane & 15, quad = lane >> 4, rb = quad * 4;
    const int p  = wave * 16 + fr;

    const ushort_t* kb = k_ws + (size_t)bh * T_ * HD_ + jn * 16;
    const uint4*    vp = (const uint4*)(v_ws + (size_t)bh * T_ * HD_);

    const int ks = tid >> 1;
    const int ng = (tid & 1) * 8;

    uint4 kv = *(const uint4*)(kb + ks * HD_ + ng);
    uint4 vv[4];
    #pragma unroll
    for (int g = 0; g < 4; g++) vv[g] = vp[tid + 256 * g];

    f32x4 accs = (f32x4){0.f, 0.f, 0.f, 0.f};

    for (int c = 0; c < NC; c++) {
        const int buf = c & 1;
        scatter_T(vv, VtS[buf], tid);
        {
            ushort_t e[8];
            *(uint4*)e = kv;
            const int sb = ks >> 3, slo = ks & 7;
            #pragma unroll
            for (int j = 0; j < 8; j++) {
                const int nl  = ng + j;
                const int blk = (sb & 8) | ((sb ^ (nl >> 3)) & 7);
                KtS[buf][nl * LDS_ + (blk << 3) + slo] = e[j];
            }
        }
        __syncthreads();

        if (c + 1 < NC) {
            kv = *(const uint4*)(kb + (size_t)(c + 1) * CHK * HD_ + ks * HD_ + ng);
            const int off = (c + 1) * 1024;
            #pragma unroll
            for (int g = 0; g < 4; g++) vv[g] = vp[off + tid + 256 * g];
        }

        ushort_t* sp = states_bf + ((size_t)bh * NC + c) * 4096;
        #pragma unroll
        for (int r = 0; r < 4; r++)
            sp[(wave * 16 + rb + r) * 64 + jn * 16 + fr] = f2bf(accs[r]);

        #pragma unroll
        for (int kt = 0; kt < 4; kt++) {
            const int sb   = kt * 4 + quad;
            const int blkA = (sb & 8) | ((sb ^ (p >> 3)) & 7);
            bf16x8 af = __builtin_bit_cast(bf16x8,
                *(const uint4*)&VtS[buf][p * LDS_ + (blkA << 3)]);
            const int blkB = (sb & 8) | ((sb ^ (fr >> 3)) & 7);
            uint4 ub = *(const uint4*)&KtS[buf][fr * LDS_ + (blkB << 3)];
            accs = __builtin_amdgcn_mfma_f32_16x16x32_bf16(
                af, __builtin_bit_cast(bf16x8, ub), accs, 0, 0, 0);
        }
    }
}

// ---------------- per-chunk attention (MFMA, precomputed bf16 states) ----------------
__global__ __launch_bounds__(256) void attn_chunk(
    const ushort_t* __restrict__ q_ws, const ushort_t* __restrict__ k_ws,
    const ushort_t* __restrict__ v_ws, const ushort_t* __restrict__ states_bf,
    ushort_t* __restrict__ y_ws)
{
    const int c = blockIdx.x, bh = blockIdx.y;
    __shared__ __align__(16) ushort_t VtS[64 * LDS_];    // V^T [p][s] swizzled
    __shared__ __align__(16) ushort_t Smat[128 * LDS_];  // masked scores [t][s]

    const int tid  = threadIdx.x;
    const int wave = tid >> 6;
    const int lane = tid & 63;
    const int fr   = lane & 15;
    const int quad = lane >> 4;
    const int fk   = quad * 8;
    const int rb   = quad * 4;

    const size_t base = ((size_t)bh * T_ + (size_t)c * CHK) * HD_;
    const ushort_t* qg = q_ws + base;
    const ushort_t* kg = k_ws + base;
    const ushort_t* vg = v_ws + base;
    const ushort_t* st = states_bf + ((size_t)bh * NC + c) * 4096;

    stage_T(vg, VtS, tid);
    __syncthreads();

    const int mt[2] = { wave, 7 - wave };

    bf16x8 aq[2][2];
    #pragma unroll
    for (int i = 0; i < 2; i++)
        #pragma unroll
        for (int kk = 0; kk < 2; kk++) {
            uint4 u = *(const uint4*)(qg + (mt[i] * 16 + fr) * HD_ + kk * 32 + fk);
            aq[i][kk] = __builtin_bit_cast(bf16x8, u);
        }

    f32x4 acc[2][4];
    #pragma unroll
    for (int i = 0; i < 2; i++)
        #pragma unroll
        for (int jn = 0; jn < 4; jn++)
            acc[i][jn] = (f32x4){0.f, 0.f, 0.f, 0.f};

    // inter-chunk: acc += Q . S_prev^T (bf16 states direct)
    #pragma unroll
    for (int jn = 0; jn < 4; jn++) {
        #pragma unroll
        for (int kk = 0; kk < 2; kk++) {
            uint4 u = *(const uint4*)(st + (jn * 16 + fr) * 64 + kk * 32 + fk);
            bf16x8 bsp = __builtin_bit_cast(bf16x8, u);
            #pragma unroll
            for (int i = 0; i < 2; i++)
                acc[i][jn] = __builtin_amdgcn_mfma_f32_16x16x32_bf16(
                    aq[i][kk], bsp, acc[i][jn], 0, 0, 0);
        }
    }

    // per m-tile: scores -> mask -> Smat -> PV
    #pragma unroll
    for (int i = 0; i < 2; i++) {
        const int m  = mt[i];
        const int nk = (m + 2) >> 1;
        const int jt = 2 * nk;

        f32x4 sc[8];
        #pragma unroll
        for (int j = 0; j < 8; j++) sc[j] = (f32x4){0.f, 0.f, 0.f, 0.f};

        #pragma unroll
        for (int j = 0; j < 8; j++) {
            if (j <= m) {
                #pragma unroll
                for (int kk = 0; kk < 2; kk++) {
                    uint4 u = *(const uint4*)(kg + (j * 16 + fr) * HD_ + kk * 32 + fk);
                    sc[j] = __builtin_amdgcn_mfma_f32_16x16x32_bf16(
                        aq[i][kk], __builtin_bit_cast(bf16x8, u), sc[j], 0, 0, 0);
                }
            }
        }

        #pragma unroll
        for (int j = 0; j < 8; j++) {
            if (j < jt) {
                f32x4 v = sc[j];
                if (j == m) {
                    #pragma unroll
                    for (int r = 0; r < 4; r++)
                        if (fr > rb + r) v[r] = 0.f;
                }
                #pragma unroll
                for (int r = 0; r < 4; r++)
                    Smat[(m * 16 + rb + r) * LDS_ + j * 16 + fr] = f2bf(v[r]);
            }
        }

        #pragma unroll
        for (int kt = 0; kt < 4; kt++) {
            if (kt < nk) {
                uint4 ua = *(const uint4*)&Smat[(m * 16 + fr) * LDS_ + kt * 32 + fk];
                bf16x8 as_ = __builtin_bit_cast(bf16x8, ua);
                #pragma unroll
                for (int jn = 0; jn < 4; jn++) {
                    const int p   = jn * 16 + fr;
                    const int sb  = kt * 4 + quad;
                    const int blk = (sb & 8) | ((sb ^ (p >> 3)) & 7);
                    uint4 ub = *(const uint4*)&VtS[p * LDS_ + (blk << 3)];
                    acc[i][jn] = __builtin_amdgcn_mfma_f32_16x16x32_bf16(
                        as_, __builtin_bit_cast(bf16x8, ub), acc[i][jn], 0, 0, 0);
                }
            }
        }
    }

    const int b = bh >> 4, h = bh & 15;
    ushort_t* yg = y_ws + ((size_t)(b * T_ + c * CHK)) * D_ + h * 64;
    #pragma unroll
    for (int i = 0; i < 2; i++) {
        #pragma unroll
        for (int jn = 0; jn < 4; jn++) {
            #pragma unroll
            for (int r = 0; r < 4; r++) {
                const int t = mt[i] * 16 + rb + r;
                const int p = jn * 16 + fr;
                yg[(size_t)t * D_ + p] = f2bf(acc[i][jn][r]);
            }
        }
    }
}

// ---------------- launch ----------------
extern "C" void kernel_launch(void* const* d_in, const int* in_sizes, int n_in,
                              void* d_out, int out_size, void* d_ws, size_t ws_size,
                              hipStream_t stream)
{
    const float* x  = (const float*)d_in[0];
    const float* Wq = (const float*)d_in[1];
    const float* bq = (const float*)d_in[2];
    const float* Wk = (const float*)d_in[3];
    const float* bk = (const float*)d_in[4];
    const float* Wv = (const float*)d_in[5];
    const float* bv = (const float*)d_in[6];
    const float* Wo = (const float*)d_in[7];
    const float* bo = (const float*)d_in[8];
    float* out = (float*)d_out;

    // ws layout (ushort elems): [xb 4M][Wqb 1M][Wkb 1M][Wvb 1M][Wob 1M][q 4M][k 4M][v 4M][y 4M] = 48 MB
    ushort_t* cvt    = (ushort_t*)d_ws;
    ushort_t* xb     = cvt;
    ushort_t* Wqkvb  = cvt + (size_t)XN;
    ushort_t* Wob    = cvt + (size_t)XN + 3 * WN;
    ushort_t* q_ws   = cvt + (size_t)XN + 4 * WN;
    ushort_t* k_ws   = q_ws + (size_t)M_ * D_;
    ushort_t* v_ws   = k_ws + (size_t)M_ * D_;
    ushort_t* y_ws   = v_ws + (size_t)M_ * D_;
    ushort_t* states_bf = Wqkvb;   // alias into dead Wqb+Wkb region, 4 MB

    to_bf16_all<<<dim3((XN + 4 * WN) / 8 / 256), 256, 0, stream>>>(
        x, Wq, Wk, Wv, Wo, cvt);
    gemm_qkv<<<dim3(768), 256, 0, stream>>>(
        xb, Wqkvb, bq, bk, bv, q_ws);
    chunk_states<<<dim3(4, BH), 256, 0, stream>>>(k_ws, v_ws, states_bf);
    attn_chunk<<<dim3(NC, BH), 256, 0, stream>>>(q_ws, k_ws, v_ws, states_bf, y_ws);
    gemm_out<<<dim3(512), 256, 0, stream>>>(y_ws, Wob, bo, out);
}

// Round 13
// 172.368 us; speedup vs baseline: 1.1185x; 1.0505x over previous
//
#include <hip/hip_runtime.h>
#include <stdint.h>

#define B_  2
#define T_  2048
#define D_  1024
#define H_  16
#define HD_ 64
#define M_  (B_*T_)      // 4096
#define CHK 128          // time chunk
#define NC  (T_/CHK)     // 16
#define BH  (B_*H_)      // 32

#define XN   4194304     // x elems (4 M)
#define WN   1048576     // one W elems (1 M)

typedef unsigned short ushort_t;
typedef unsigned int   uint_t;

typedef __bf16 bf16x8 __attribute__((ext_vector_type(8)));
typedef float  f32x4  __attribute__((ext_vector_type(4)));

// ---------- bf16 helpers ----------
__device__ inline ushort_t f2bf(float f) {
    uint_t x = __float_as_uint(f);
    x += 0x7fffu + ((x >> 16) & 1u);   // RNE
    return (ushort_t)(x >> 16);
}

__device__ inline uint4 pack8(const float4& lo, const float4& hi) {
    uint4 pk;
    pk.x = (uint_t)f2bf(lo.x) | ((uint_t)f2bf(lo.y) << 16);
    pk.y = (uint_t)f2bf(lo.z) | ((uint_t)f2bf(lo.w) << 16);
    pk.z = (uint_t)f2bf(hi.x) | ((uint_t)f2bf(hi.y) << 16);
    pk.w = (uint_t)f2bf(hi.z) | ((uint_t)f2bf(hi.w) << 16);
    return pk;
}

// ---------------- fp32 -> bf16 pre-conversion (one contiguous dest) ----------------
__global__ __launch_bounds__(256) void to_bf16_all(
    const float* __restrict__ x,  const float* __restrict__ Wq,
    const float* __restrict__ Wk, const float* __restrict__ Wv,
    const float* __restrict__ Wo, ushort_t* __restrict__ dst)
{
    const int idx = blockIdx.x * 256 + threadIdx.x;
    const int e   = idx * 8;
    const float* src;
    if      (e < XN)          src = x  + e;
    else if (e < XN + WN)     src = Wq + (e - XN);
    else if (e < XN + 2*WN)   src = Wk + (e - XN - WN);
    else if (e < XN + 3*WN)   src = Wv + (e - XN - 2*WN);
    else                      src = Wo + (e - XN - 3*WN);
    float4 lo = ((const float4*)src)[0];
    float4 hi = ((const float4*)src)[1];
    *(uint4*)(dst + e) = pack8(lo, hi);
}

// ---------------- m97-style bf16 GEMM core pieces ----------------
__device__ inline void stage_rows(const ushort_t* __restrict__ g, ushort_t* ldsw,
                                  int lane, int issues) {
    const int rr  = lane >> 3;
    const int kg8 = ((lane & 7) ^ rr) << 3;
    const ushort_t* src = g + (size_t)rr * D_ + kg8;
    #pragma unroll
    for (int i = 0; i < issues; i++) {
        __builtin_amdgcn_global_load_lds(
            (const __attribute__((address_space(1))) void*)(src + (size_t)(i * 8) * D_),
            (__attribute__((address_space(3))) void*)(ldsw + i * 512),
            16, 0, 0);
    }
}

// Fused QKV projection. Tile 64m x 128n -> 1536 blocks = 6 blocks/CU
// (128x128 was 768 = exactly 3/CU: grid-capped co-residency, latency-bound
// per r11 counters MfmaUtil 21 / VALU 17 / Occ 14). XCD rectangle decode:
// XCD r owns 16 m-tiles x 4 n-tiles x 3 z.
__global__ __launch_bounds__(256) void gemm_qkv(
    const ushort_t* __restrict__ xb, const ushort_t* __restrict__ Wqkvb,
    const float* __restrict__ bq, const float* __restrict__ bk,
    const float* __restrict__ bv, ushort_t* __restrict__ qkv_ws)
{
    const int flat = blockIdx.x;          // 0..1535
    const int r    = flat & 7;            // XCD (assumed flat%8 placement)
    const int j    = flat >> 3;           // 0..191
    const int mt   = ((r >> 1) << 4) | (j & 15);        // m-tile 0..63
    const int nt   = ((r & 1) << 2) | ((j >> 4) & 3);   // n-tile 0..7
    const int z    = j >> 6;                            // 0..2

    const ushort_t* W  = Wqkvb + (size_t)z * WN;
    const float*    bi = (z == 0) ? bq : ((z == 1) ? bk : bv);
    ushort_t* out = qkv_ws + (size_t)z * (size_t)M_ * D_;

    __shared__ __align__(16) ushort_t As[64 * 64];    // 8 KB
    __shared__ __align__(16) ushort_t Bs[128 * 64];   // 16 KB

    const int tid  = threadIdx.x;
    const int m0   = mt * 64;
    const int n0   = nt * 128;
    const int wave = tid >> 6;
    const int lane = tid & 63;
    const int wm   = (wave >> 1) * 32;
    const int wn   = (wave & 1) * 64;
    const int fr   = lane & 15;
    const int quad = lane >> 4;

    const ushort_t* Ag = xb + (size_t)(m0 + wave * 16) * D_;
    const ushort_t* Bg = W  + (size_t)(n0 + wave * 32) * D_;
    ushort_t* Alds = &As[wave * 16 * 64];
    ushort_t* Blds = &Bs[wave * 32 * 64];

    f32x4 acc[2][4];
    #pragma unroll
    for (int i = 0; i < 2; i++)
        #pragma unroll
        for (int j2 = 0; j2 < 4; j2++)
            acc[i][j2] = (f32x4){0.f, 0.f, 0.f, 0.f};

    for (int k0 = 0; k0 < D_; k0 += 64) {
        __syncthreads();
        stage_rows(Ag + k0, Alds, lane, 2);   // A: 16 rows/wave
        stage_rows(Bg + k0, Blds, lane, 4);   // B: 32 rows/wave
        __syncthreads();

        #pragma unroll
        for (int ksg = 0; ksg <= 4; ksg += 4) {
            const int kgo = ((ksg + quad) ^ (fr & 7)) << 3;
            bf16x8 af[2], bf[4];
            #pragma unroll
            for (int i = 0; i < 2; i++) {
                uint4 u = *(const uint4*)&As[(wm + i * 16 + fr) * 64 + kgo];
                af[i] = __builtin_bit_cast(bf16x8, u);
            }
            #pragma unroll
            for (int j2 = 0; j2 < 4; j2++) {
                uint4 u = *(const uint4*)&Bs[(wn + j2 * 16 + fr) * 64 + kgo];
                bf[j2] = __builtin_bit_cast(bf16x8, u);
            }
            #pragma unroll
            for (int i = 0; i < 2; i++)
                #pragma unroll
                for (int j2 = 0; j2 < 4; j2++)
                    acc[i][j2] = __builtin_amdgcn_mfma_f32_16x16x32_bf16(
                        af[i], bf[j2], acc[i][j2], 0, 0, 0);
        }
    }

    // epilogue: split heads, scalar stores (LDS repack regressed in r10)
    const int rb = quad * 4;
    #pragma unroll
    for (int j2 = 0; j2 < 4; j2++) {
        const int n = n0 + wn + j2 * 16 + fr;
        const float bias = bi[n];
        const int h  = n >> 6;
        const int hd = n & 63;
        #pragma unroll
        for (int i = 0; i < 2; i++) {
            #pragma unroll
            for (int rr = 0; rr < 4; rr++) {
                const int m = m0 + wm + i * 16 + rb + rr;
                const int b = m >> 11, t = m & (T_ - 1);
                out[(((size_t)(b * H_ + h)) * T_ + t) * HD_ + hd] =
                    f2bf(acc[i][j2][rr] + bias);
            }
        }
    }
}

// Output projection: A = y_ws bf16 [M][D], B = Wob bf16, out fp32 + bias.
// Tile 64m x 128n, 1-D grid 512, XCD rectangle 16m x 4n per XCD.
__global__ __launch_bounds__(256) void gemm_out(
    const ushort_t* __restrict__ Yw, const ushort_t* __restrict__ Wob,
    const float* __restrict__ bo, float* __restrict__ out)
{
    const int flat = blockIdx.x;          // 0..511
    const int r    = flat & 7;
    const int j    = flat >> 3;           // 0..63
    const int mt   = ((r >> 1) << 4) | (j & 15);   // 0..63
    const int nt   = ((r & 1) << 2) | (j >> 4);    // 0..7

    __shared__ __align__(16) ushort_t As[64 * 64];
    __shared__ __align__(16) ushort_t Bs[128 * 64];

    const int tid  = threadIdx.x;
    const int m0   = mt * 64;
    const int n0   = nt * 128;
    const int wave = tid >> 6;
    const int lane = tid & 63;
    const int wm   = (wave >> 1) * 32;
    const int wn   = (wave & 1) * 64;
    const int fr   = lane & 15;
    const int quad = lane >> 4;

    const ushort_t* Ag = Yw  + (size_t)(m0 + wave * 16) * D_;
    const ushort_t* Bg = Wob + (size_t)(n0 + wave * 32) * D_;
    ushort_t* Alds = &As[wave * 16 * 64];
    ushort_t* Blds = &Bs[wave * 32 * 64];

    f32x4 acc[2][4];
    #pragma unroll
    for (int i = 0; i < 2; i++)
        #pragma unroll
        for (int j2 = 0; j2 < 4; j2++)
            acc[i][j2] = (f32x4){0.f, 0.f, 0.f, 0.f};

    for (int k0 = 0; k0 < D_; k0 += 64) {
        __syncthreads();
        stage_rows(Ag + k0, Alds, lane, 2);
        stage_rows(Bg + k0, Blds, lane, 4);
        __syncthreads();

        #pragma unroll
        for (int ksg = 0; ksg <= 4; ksg += 4) {
            const int kgo = ((ksg + quad) ^ (fr & 7)) << 3;
            bf16x8 af[2], bf[4];
            #pragma unroll
            for (int i = 0; i < 2; i++) {
                uint4 u = *(const uint4*)&As[(wm + i * 16 + fr) * 64 + kgo];
                af[i] = __builtin_bit_cast(bf16x8, u);
            }
            #pragma unroll
            for (int j2 = 0; j2 < 4; j2++) {
                uint4 u = *(const uint4*)&Bs[(wn + j2 * 16 + fr) * 64 + kgo];
                bf[j2] = __builtin_bit_cast(bf16x8, u);
            }
            #pragma unroll
            for (int i = 0; i < 2; i++)
                #pragma unroll
                for (int j2 = 0; j2 < 4; j2++)
                    acc[i][j2] = __builtin_amdgcn_mfma_f32_16x16x32_bf16(
                        af[i], bf[j2], acc[i][j2], 0, 0, 0);
        }
    }

    const int rb = quad * 4;
    #pragma unroll
    for (int j2 = 0; j2 < 4; j2++) {
        const int n = n0 + wn + j2 * 16 + fr;
        const float bias = bo[n];
        #pragma unroll
        for (int i = 0; i < 2; i++) {
            #pragma unroll
            for (int rr = 0; rr < 4; rr++) {
                const int m = m0 + wm + i * 16 + rb + rr;
                out[(size_t)m * D_ + n] = acc[i][j2][rr] + bias;
            }
        }
    }
}

#define LDS_ 136   // row stride (ushorts): 272 B = 68 dwords = 4-bank rotation

// swizzled transpose scatter from registers: uint4 g of [128][64] tile ->
// dst[row][blk*8 + s&7], blk = (sb&8) | ((sb ^ (row>>3)) & 7).  (proven)
__device__ inline void scatter_T(const uint4* u, ushort_t* dst, int tid) {
    #pragma unroll
    for (int g = 0; g < 4; g++) {
        const int v  = tid + 256 * g;
        const int s  = v >> 3;
        const int p8 = (v & 7) * 8;
        ushort_t e[8];
        *(uint4*)e = u[g];
        const int sb = s >> 3, slo = s & 7;
        #pragma unroll
        for (int j = 0; j < 8; j++) {
            const int p   = p8 + j;
            const int blk = (sb & 8) | ((sb ^ (p >> 3)) & 7);
            dst[p * LDS_ + (blk << 3) + slo] = e[j];
        }
    }
}

__device__ inline void stage_T(const ushort_t* __restrict__ src, ushort_t* dst, int tid) {
    uint4 u[4];
    #pragma unroll
    for (int g = 0; g < 4; g++) u[g] = ((const uint4*)src)[tid + 256 * g];
    scatter_T(u, dst, tid);
}

// ---------------- fused chunk deltas + exclusive prefix, n-split 4x ----------------
__global__ __launch_bounds__(256) void chunk_states(
    const ushort_t* __restrict__ k_ws, const ushort_t* __restrict__ v_ws,
    ushort_t* __restrict__ states_bf)
{
    const int jn = blockIdx.x;          // n-tile 0..3
    const int bh = blockIdx.y;
    __shared__ __align__(16) ushort_t VtS[2][64 * LDS_];   // 34 KB
    __shared__ __align__(16) ushort_t KtS[2][16 * LDS_];   // 8.5 KB

    const int tid  = threadIdx.x;
    const int wave = tid >> 6, lane = tid & 63;
    const int fr = lane & 15, quad = lane >> 4, rb = quad * 4;
    const int p  = wave * 16 + fr;

    const ushort_t* kb = k_ws + (size_t)bh * T_ * HD_ + jn * 16;
    const uint4*    vp = (const uint4*)(v_ws + (size_t)bh * T_ * HD_);

    const int ks = tid >> 1;
    const int ng = (tid & 1) * 8;

    uint4 kv = *(const uint4*)(kb + ks * HD_ + ng);
    uint4 vv[4];
    #pragma unroll
    for (int g = 0; g < 4; g++) vv[g] = vp[tid + 256 * g];

    f32x4 accs = (f32x4){0.f, 0.f, 0.f, 0.f};

    for (int c = 0; c < NC; c++) {
        const int buf = c & 1;
        scatter_T(vv, VtS[buf], tid);
        {
            ushort_t e[8];
            *(uint4*)e = kv;
            const int sb = ks >> 3, slo = ks & 7;
            #pragma unroll
            for (int j = 0; j < 8; j++) {
                const int nl  = ng + j;
                const int blk = (sb & 8) | ((sb ^ (nl >> 3)) & 7);
                KtS[buf][nl * LDS_ + (blk << 3) + slo] = e[j];
            }
        }
        __syncthreads();

        if (c + 1 < NC) {
            kv = *(const uint4*)(kb + (size_t)(c + 1) * CHK * HD_ + ks * HD_ + ng);
            const int off = (c + 1) * 1024;
            #pragma unroll
            for (int g = 0; g < 4; g++) vv[g] = vp[off + tid + 256 * g];
        }

        ushort_t* sp = states_bf + ((size_t)bh * NC + c) * 4096;
        #pragma unroll
        for (int r = 0; r < 4; r++)
            sp[(wave * 16 + rb + r) * 64 + jn * 16 + fr] = f2bf(accs[r]);

        #pragma unroll
        for (int kt = 0; kt < 4; kt++) {
            const int sb   = kt * 4 + quad;
            const int blkA = (sb & 8) | ((sb ^ (p >> 3)) & 7);
            bf16x8 af = __builtin_bit_cast(bf16x8,
                *(const uint4*)&VtS[buf][p * LDS_ + (blkA << 3)]);
            const int blkB = (sb & 8) | ((sb ^ (fr >> 3)) & 7);
            uint4 ub = *(const uint4*)&KtS[buf][fr * LDS_ + (blkB << 3)];
            accs = __builtin_amdgcn_mfma_f32_16x16x32_bf16(
                af, __builtin_bit_cast(bf16x8, ub), accs, 0, 0, 0);
        }
    }
}

// ---------------- per-chunk attention (MFMA, precomputed bf16 states) ----------------
__global__ __launch_bounds__(256) void attn_chunk(
    const ushort_t* __restrict__ q_ws, const ushort_t* __restrict__ k_ws,
    const ushort_t* __restrict__ v_ws, const ushort_t* __restrict__ states_bf,
    ushort_t* __restrict__ y_ws)
{
    const int c = blockIdx.x, bh = blockIdx.y;
    __shared__ __align__(16) ushort_t VtS[64 * LDS_];    // V^T [p][s] swizzled
    __shared__ __align__(16) ushort_t Smat[128 * LDS_];  // masked scores [t][s]

    const int tid  = threadIdx.x;
    const int wave = tid >> 6;
    const int lane = tid & 63;
    const int fr   = lane & 15;
    const int quad = lane >> 4;
    const int fk   = quad * 8;
    const int rb   = quad * 4;

    const size_t base = ((size_t)bh * T_ + (size_t)c * CHK) * HD_;
    const ushort_t* qg = q_ws + base;
    const ushort_t* kg = k_ws + base;
    const ushort_t* vg = v_ws + base;
    const ushort_t* st = states_bf + ((size_t)bh * NC + c) * 4096;

    stage_T(vg, VtS, tid);
    __syncthreads();

    const int mt[2] = { wave, 7 - wave };

    bf16x8 aq[2][2];
    #pragma unroll
    for (int i = 0; i < 2; i++)
        #pragma unroll
        for (int kk = 0; kk < 2; kk++) {
            uint4 u = *(const uint4*)(qg + (mt[i] * 16 + fr) * HD_ + kk * 32 + fk);
            aq[i][kk] = __builtin_bit_cast(bf16x8, u);
        }

    f32x4 acc[2][4];
    #pragma unroll
    for (int i = 0; i < 2; i++)
        #pragma unroll
        for (int jn = 0; jn < 4; jn++)
            acc[i][jn] = (f32x4){0.f, 0.f, 0.f, 0.f};

    // inter-chunk: acc += Q . S_prev^T (bf16 states direct)
    #pragma unroll
    for (int jn = 0; jn < 4; jn++) {
        #pragma unroll
        for (int kk = 0; kk < 2; kk++) {
            uint4 u = *(const uint4*)(st + (jn * 16 + fr) * 64 + kk * 32 + fk);
            bf16x8 bsp = __builtin_bit_cast(bf16x8, u);
            #pragma unroll
            for (int i = 0; i < 2; i++)
                acc[i][jn] = __builtin_amdgcn_mfma_f32_16x16x32_bf16(
                    aq[i][kk], bsp, acc[i][jn], 0, 0, 0);
        }
    }

    // per m-tile: scores -> mask -> Smat -> PV
    #pragma unroll
    for (int i = 0; i < 2; i++) {
        const int m  = mt[i];
        const int nk = (m + 2) >> 1;
        const int jt = 2 * nk;

        f32x4 sc[8];
        #pragma unroll
        for (int j = 0; j < 8; j++) sc[j] = (f32x4){0.f, 0.f, 0.f, 0.f};

        #pragma unroll
        for (int j = 0; j < 8; j++) {
            if (j <= m) {
                #pragma unroll
                for (int kk = 0; kk < 2; kk++) {
                    uint4 u = *(const uint4*)(kg + (j * 16 + fr) * HD_ + kk * 32 + fk);
                    sc[j] = __builtin_amdgcn_mfma_f32_16x16x32_bf16(
                        aq[i][kk], __builtin_bit_cast(bf16x8, u), sc[j], 0, 0, 0);
                }
            }
        }

        #pragma unroll
        for (int j = 0; j < 8; j++) {
            if (j < jt) {
                f32x4 v = sc[j];
                if (j == m) {
                    #pragma unroll
                    for (int r = 0; r < 4; r++)
                        if (fr > rb + r) v[r] = 0.f;
                }
                #pragma unroll
                for (int r = 0; r < 4; r++)
                    Smat[(m * 16 + rb + r) * LDS_ + j * 16 + fr] = f2bf(v[r]);
            }
        }

        #pragma unroll
        for (int kt = 0; kt < 4; kt++) {
            if (kt < nk) {
                uint4 ua = *(const uint4*)&Smat[(m * 16 + fr) * LDS_ + kt * 32 + fk];
                bf16x8 as_ = __builtin_bit_cast(bf16x8, ua);
                #pragma unroll
                for (int jn = 0; jn < 4; jn++) {
                    const int p   = jn * 16 + fr;
                    const int sb  = kt * 4 + quad;
                    const int blk = (sb & 8) | ((sb ^ (p >> 3)) & 7);
                    uint4 ub = *(const uint4*)&VtS[p * LDS_ + (blk << 3)];
                    acc[i][jn] = __builtin_amdgcn_mfma_f32_16x16x32_bf16(
                        as_, __builtin_bit_cast(bf16x8, ub), acc[i][jn], 0, 0, 0);
                }
            }
        }
    }

    const int b = bh >> 4, h = bh & 15;
    ushort_t* yg = y_ws + ((size_t)(b * T_ + c * CHK)) * D_ + h * 64;
    #pragma unroll
    for (int i = 0; i < 2; i++) {
        #pragma unroll
        for (int jn = 0; jn < 4; jn++) {
            #pragma unroll
            for (int r = 0; r < 4; r++) {
                const int t = mt[i] * 16 + rb + r;
                const int p = jn * 16 + fr;
                yg[(size_t)t * D_ + p] = f2bf(acc[i][jn][r]);
            }
        }
    }
}

// ---------------- launch ----------------
extern "C" void kernel_launch(void* const* d_in, const int* in_sizes, int n_in,
                              void* d_out, int out_size, void* d_ws, size_t ws_size,
                              hipStream_t stream)
{
    const float* x  = (const float*)d_in[0];
    const float* Wq = (const float*)d_in[1];
    const float* bq = (const float*)d_in[2];
    const float* Wk = (const float*)d_in[3];
    const float* bk = (const float*)d_in[4];
    const float* Wv = (const float*)d_in[5];
    const float* bv = (const float*)d_in[6];
    const float* Wo = (const float*)d_in[7];
    const float* bo = (const float*)d_in[8];
    float* out = (float*)d_out;

    // ws layout (ushort elems): [xb 4M][Wqb 1M][Wkb 1M][Wvb 1M][Wob 1M][q 4M][k 4M][v 4M][y 4M] = 48 MB
    ushort_t* cvt    = (ushort_t*)d_ws;
    ushort_t* xb     = cvt;
    ushort_t* Wqkvb  = cvt + (size_t)XN;
    ushort_t* Wob    = cvt + (size_t)XN + 3 * WN;
    ushort_t* q_ws   = cvt + (size_t)XN + 4 * WN;
    ushort_t* k_ws   = q_ws + (size_t)M_ * D_;
    ushort_t* v_ws   = k_ws + (size_t)M_ * D_;
    ushort_t* y_ws   = v_ws + (size_t)M_ * D_;
    ushort_t* states_bf = Wqkvb;   // alias into dead Wqb+Wkb region, 4 MB

    to_bf16_all<<<dim3((XN + 4 * WN) / 8 / 256), 256, 0, stream>>>(
        x, Wq, Wk, Wv, Wo, cvt);
    gemm_qkv<<<dim3(1536), 256, 0, stream>>>(
        xb, Wqkvb, bq, bk, bv, q_ws);
    chunk_states<<<dim3(4, BH), 256, 0, stream>>>(k_ws, v_ws, states_bf);
    attn_chunk<<<dim3(NC, BH), 256, 0, stream>>>(q_ws, k_ws, v_ws, states_bf, y_ws);
    gemm_out<<<dim3(512), 256, 0, stream>>>(y_ws, Wob, bo, out);
}